// Round 1
// baseline (939.013 us; speedup 1.0000x reference)
//
#include <hip/hip_runtime.h>
#include <hip/hip_bf16.h>

#define D_IN 128
#define D_CAT 256

// ---------------- CSR build ----------------

__global__ void hist_kernel(const int* __restrict__ dst, int* __restrict__ cnt, int E) {
    for (int e = blockIdx.x * blockDim.x + threadIdx.x; e < E; e += gridDim.x * blockDim.x)
        atomicAdd(&cnt[dst[e]], 1);
}

// single-block hierarchical exclusive scan of cnt[0..n) -> offsets[0..n], pos[0..n)
__global__ __launch_bounds__(1024) void scan_kernel(const int* __restrict__ cnt,
                                                    int* __restrict__ offsets,
                                                    int* __restrict__ pos, int n) {
    __shared__ int wtot[16];
    __shared__ int woff[16];
    __shared__ int s_run, s_chunk;
    int t = threadIdx.x;
    int lane = t & 63, wv = t >> 6;
    if (t == 0) s_run = 0;
    __syncthreads();
    for (int base = 0; base < n; base += 1024) {
        int i = base + t;
        int v = (i < n) ? cnt[i] : 0;
        // inclusive scan within wave
        int x = v;
#pragma unroll
        for (int o = 1; o < 64; o <<= 1) {
            int y = __shfl_up(x, o, 64);
            if (lane >= o) x += y;
        }
        if (lane == 63) wtot[wv] = x;
        __syncthreads();
        if (wv == 0) {
            int wval = (lane < 16) ? wtot[lane] : 0;
            int wx = wval;
#pragma unroll
            for (int o = 1; o < 16; o <<= 1) {
                int y = __shfl_up(wx, o, 64);
                if (lane >= o) wx += y;
            }
            if (lane < 16) woff[lane] = wx - wval;
            if (lane == 15) s_chunk = wx;
        }
        __syncthreads();
        int run = s_run;
        int incl = x + woff[wv];
        if (i < n) {
            int e = run + incl - v;  // exclusive
            offsets[i] = e;
            pos[i] = e;
        }
        __syncthreads();  // everyone read s_run before update
        if (t == 0) s_run = run + s_chunk;
        __syncthreads();
    }
    if (t == 0) offsets[n] = s_run;
}

__global__ void scatter_kernel(const int* __restrict__ src, const int* __restrict__ dst,
                               int* __restrict__ pos, int* __restrict__ csr_src, int E) {
    for (int e = blockIdx.x * blockDim.x + threadIdx.x; e < E; e += gridDim.x * blockDim.x) {
        int d = dst[e];
        int p = atomicAdd(&pos[d], 1);
        csr_src[p] = src[e];
    }
}

// W [rows, cols] -> WT [cols, rows]
__global__ void transpose_kernel(const float* __restrict__ W, float* __restrict__ WT,
                                 int rows, int cols) {
    int i = blockIdx.x * blockDim.x + threadIdx.x;
    if (i < rows * cols) {
        int r = i / cols, c = i % cols;
        WT[c * rows + r] = W[i];
    }
}

// ---------------- fused layer: mean-agg -> concat -> GEMM (-> relu) ----------------
// F: [n, 128] input features. WT: [256, D_OUT] (transposed weight).
// 256 threads, 4 nodes per block: wave w aggregates node blockIdx.x*4+w.
template <int D_OUT, bool RELU>
__global__ __launch_bounds__(256) void fused_layer(const float* __restrict__ F,
                                                   const int* __restrict__ offsets,
                                                   const int* __restrict__ csr_src,
                                                   const float* __restrict__ WT,
                                                   float* __restrict__ Hout, int n) {
    __shared__ float cvec[4][D_CAT];
    int w = threadIdx.x >> 6;
    int lane = threadIdx.x & 63;
    int v = blockIdx.x * 4 + w;
    if (v < n) {
        int beg = offsets[v], end = offsets[v + 1];
        float a0 = 0.f, a1 = 0.f;
        for (int i = beg; i < end; ++i) {
            int s = csr_src[i];
            float2 f2 = *(const float2*)(F + (size_t)s * D_IN + 2 * lane);
            a0 += f2.x;
            a1 += f2.y;
        }
        int deg = end - beg;
        float inv = 1.0f / (float)(deg > 0 ? deg : 1);
        float2 sf = *(const float2*)(F + (size_t)v * D_IN + 2 * lane);
        cvec[w][2 * lane] = sf.x;
        cvec[w][2 * lane + 1] = sf.y;
        cvec[w][D_IN + 2 * lane] = a0 * inv;
        cvec[w][D_IN + 2 * lane + 1] = a1 * inv;
    }
    __syncthreads();

    int t = threadIdx.x;
    if constexpr (D_OUT == 128) {
        int j = t & 127, wb = t >> 7;  // nodes wb and wb+2
        int v0 = blockIdx.x * 4 + wb, v1 = v0 + 2;
        float acc0 = 0.f, acc1 = 0.f;
#pragma unroll 8
        for (int k = 0; k < D_CAT; ++k) {
            float wt = WT[k * 128 + j];
            acc0 += cvec[wb][k] * wt;
            acc1 += cvec[wb + 2][k] * wt;
        }
        if (RELU) {
            acc0 = fmaxf(acc0, 0.f);
            acc1 = fmaxf(acc1, 0.f);
        }
        if (v0 < n) Hout[(size_t)v0 * 128 + j] = acc0;
        if (v1 < n) Hout[(size_t)v1 * 128 + j] = acc1;
    } else {  // D_OUT == 64
        int j = t & 63, wb = t >> 6;
        int v0 = blockIdx.x * 4 + wb;
        float acc = 0.f;
#pragma unroll 8
        for (int k = 0; k < D_CAT; ++k) acc += cvec[wb][k] * WT[k * 64 + j];
        if (RELU) acc = fmaxf(acc, 0.f);
        if (v0 < n) Hout[(size_t)v0 * 64 + j] = acc;
    }
}

extern "C" void kernel_launch(void* const* d_in, const int* in_sizes, int n_in,
                              void* d_out, int out_size, void* d_ws, size_t ws_size,
                              hipStream_t stream) {
    const float* feat = (const float*)d_in[0];
    const int* esrc = (const int*)d_in[1];
    const int* edst = (const int*)d_in[2];
    const float* W0 = (const float*)d_in[3];  // [128, 256]
    const float* W1 = (const float*)d_in[4];  // [64, 256]
    float* out = (float*)d_out;

    int n = in_sizes[0] / D_IN;  // 100000
    int E = in_sizes[1];         // 1600000

    char* ws = (char*)d_ws;
    size_t off = 0;
    auto alloc = [&](size_t bytes) -> void* {
        void* p = ws + off;
        off += (bytes + 255) & ~(size_t)255;
        return p;
    };
    int* cnt = (int*)alloc((size_t)n * 4);
    int* offsets = (int*)alloc((size_t)(n + 1) * 4);
    int* pos = (int*)alloc((size_t)n * 4);
    int* csr_src = (int*)alloc((size_t)E * 4);
    float* W0T = (float*)alloc((size_t)128 * 256 * 4);
    float* W1T = (float*)alloc((size_t)64 * 256 * 4);
    float* h = (float*)alloc((size_t)n * 128 * 4);

    hipMemsetAsync(cnt, 0, (size_t)n * 4, stream);
    hist_kernel<<<2048, 256, 0, stream>>>(edst, cnt, E);
    scan_kernel<<<1, 1024, 0, stream>>>(cnt, offsets, pos, n);
    scatter_kernel<<<2048, 256, 0, stream>>>(esrc, edst, pos, csr_src, E);
    transpose_kernel<<<(128 * 256 + 255) / 256, 256, 0, stream>>>(W0, W0T, 128, 256);
    transpose_kernel<<<(64 * 256 + 255) / 256, 256, 0, stream>>>(W1, W1T, 64, 256);

    int blocks = (n + 3) / 4;
    fused_layer<128, true><<<blocks, 256, 0, stream>>>(feat, offsets, csr_src, W0T, h, n);
    fused_layer<64, false><<<blocks, 256, 0, stream>>>(h, offsets, csr_src, W1T, out, n);
}

// Round 2
// 721.231 us; speedup vs baseline: 1.3020x; 1.3020x over previous
//
#include <hip/hip_runtime.h>
#include <hip/hip_bf16.h>

// ---------- helpers ----------
__device__ __forceinline__ float bf2f(unsigned short u) {
    return __uint_as_float(((unsigned int)u) << 16);
}
__device__ __forceinline__ unsigned short f2bf(float f) {
    unsigned int u = __float_as_uint(f);
    unsigned int r = u + 0x7FFFu + ((u >> 16) & 1u);  // RNE
    return (unsigned short)(r >> 16);
}

// ---------- CSR build ----------
__global__ void hist_kernel(const int* __restrict__ dst, int* __restrict__ cnt, int E) {
    for (int e = blockIdx.x * blockDim.x + threadIdx.x; e < E; e += gridDim.x * blockDim.x)
        atomicAdd(&cnt[dst[e]], 1);
}

// 3-kernel exclusive scan: A (per-block 1024), B (scan partials), C (apply base)
__global__ __launch_bounds__(256) void scanA(const int* __restrict__ cnt, int* __restrict__ offs,
                                             int* __restrict__ partials, int n) {
    __shared__ int wsum[4];
    __shared__ int woff[4];
    int t = threadIdx.x, lane = t & 63, wv = t >> 6;
    int i0 = blockIdx.x * 1024 + t * 4;
    int v0 = 0, v1 = 0, v2 = 0, v3 = 0;
    if (i0 + 3 < n) {
        int4 q = *(const int4*)(cnt + i0);
        v0 = q.x; v1 = q.y; v2 = q.z; v3 = q.w;
    } else {
        if (i0 < n) v0 = cnt[i0];
        if (i0 + 1 < n) v1 = cnt[i0 + 1];
        if (i0 + 2 < n) v2 = cnt[i0 + 2];
        if (i0 + 3 < n) v3 = cnt[i0 + 3];
    }
    int s0 = v0, s1 = s0 + v1, s2 = s1 + v2, s3 = s2 + v3;
    int x = s3;
#pragma unroll
    for (int o = 1; o < 64; o <<= 1) {
        int y = __shfl_up(x, o, 64);
        if (lane >= o) x += y;
    }
    if (lane == 63) wsum[wv] = x;
    __syncthreads();
    if (t == 0) {
        int r = 0;
        for (int w = 0; w < 4; ++w) { woff[w] = r; r += wsum[w]; }
        partials[blockIdx.x] = r;
    }
    __syncthreads();
    int base = woff[wv] + (x - s3);
    if (i0 < n) offs[i0] = base;
    if (i0 + 1 < n) offs[i0 + 1] = base + s0;
    if (i0 + 2 < n) offs[i0 + 2] = base + s1;
    if (i0 + 3 < n) offs[i0 + 3] = base + s2;
}

__global__ __launch_bounds__(128) void scanB(const int* __restrict__ partials, int* __restrict__ pbase,
                                             int nb, int* __restrict__ offs_n) {
    __shared__ int wsum[2];
    __shared__ int woff[2];
    int t = threadIdx.x, lane = t & 63, wv = t >> 6;
    int v = (t < nb) ? partials[t] : 0;
    int x = v;
#pragma unroll
    for (int o = 1; o < 64; o <<= 1) {
        int y = __shfl_up(x, o, 64);
        if (lane >= o) x += y;
    }
    if (lane == 63) wsum[wv] = x;
    __syncthreads();
    if (t == 0) { woff[0] = 0; woff[1] = wsum[0]; }
    __syncthreads();
    pbase[t] = woff[wv] + x - v;
    if (t == 127) *offs_n = woff[1] + x;
}

__global__ __launch_bounds__(256) void scanC(int* __restrict__ offs, int* __restrict__ pos,
                                             const int* __restrict__ pbase, int n) {
    int add = pbase[blockIdx.x];
    int i0 = blockIdx.x * 1024 + threadIdx.x * 4;
#pragma unroll
    for (int j = 0; j < 4; ++j) {
        int i = i0 + j;
        if (i < n) {
            int o = offs[i] + add;
            offs[i] = o;
            pos[i] = o;
        }
    }
}

__global__ void scatter_kernel(const int* __restrict__ src, const int* __restrict__ dst,
                               int* __restrict__ pos, int* __restrict__ csr_src, int E) {
    for (int e = blockIdx.x * blockDim.x + threadIdx.x; e < E; e += gridDim.x * blockDim.x) {
        int d = dst[e];
        int p = atomicAdd(&pos[d], 1);
        csr_src[p] = src[e];
    }
}

// ---------- weight prep ----------
// W0T[k][j] = W0[j][k], k in [0,256), j in [0,128)
__global__ void prep_w0t(const float* __restrict__ W0, float* __restrict__ W0T) {
    int i = blockIdx.x * 256 + threadIdx.x;  // 32768
    int k = i >> 7, j = i & 127;
    W0T[i] = W0[j * 256 + k];
}
// Wcat2[k][c]: c<64 -> W1[c][k]; c>=64 -> W1[c-64][128+k]   (k,c in [0,128))
__global__ void prep_wcat2(const float* __restrict__ W1, float* __restrict__ WC) {
    int i = blockIdx.x * 256 + threadIdx.x;  // 16384
    int k = i >> 7, c = i & 127;
    WC[i] = (c < 64) ? W1[c * 256 + k] : W1[(c - 64) * 256 + 128 + k];
}

__global__ void conv_bf16(const float* __restrict__ src, unsigned short* __restrict__ dst, int nquad) {
    for (int q = blockIdx.x * blockDim.x + threadIdx.x; q < nquad; q += gridDim.x * blockDim.x) {
        float4 f = *(const float4*)(src + (size_t)q * 4);
        ushort4 u;
        u.x = f2bf(f.x); u.y = f2bf(f.y); u.z = f2bf(f.z); u.w = f2bf(f.w);
        *(ushort4*)(dst + (size_t)q * 4) = u;
    }
}

// ---------- layer 1 fused: mean-agg(bf16 gather) -> concat -> GEMM -> relu -> bf16 ----------
// 8 nodes/block; wave w aggregates nodes 2w, 2w+1 (bf16 rows, 2 edges per wave-iter, unroll x2)
__global__ __launch_bounds__(256) void fused_l1(const unsigned short* __restrict__ Fb,
                                                const int* __restrict__ offs,
                                                const int* __restrict__ csr,
                                                const float* __restrict__ W0T,  // [256][128]
                                                unsigned short* __restrict__ Hb,
                                                int n) {
    __shared__ float cvec[8][256];
    int t = threadIdx.x, lane = t & 63, wv = t >> 6;
    int h = lane >> 5, cl = lane & 31;

    int vb = blockIdx.x * 8;
#pragma unroll
    for (int s = 0; s < 2; ++s) {
        int nd = wv * 2 + s;
        int v = vb + nd;
        float a0 = 0.f, a1 = 0.f, a2 = 0.f, a3 = 0.f;
        int beg = 0, deg = 0;
        if (v < n) { beg = offs[v]; deg = offs[v + 1] - beg; }
        int end = beg + deg;
        int e = beg + h;
        for (; e + 2 < end; e += 4) {  // edges e and e+2 for this half-wave
            int sA = csr[e], sB = csr[e + 2];
            ushort4 ua = *(const ushort4*)(Fb + sA * 128 + cl * 4);
            ushort4 ub = *(const ushort4*)(Fb + sB * 128 + cl * 4);
            a0 += bf2f(ua.x) + bf2f(ub.x);
            a1 += bf2f(ua.y) + bf2f(ub.y);
            a2 += bf2f(ua.z) + bf2f(ub.z);
            a3 += bf2f(ua.w) + bf2f(ub.w);
        }
        for (; e < end; e += 2) {
            int sA = csr[e];
            ushort4 ua = *(const ushort4*)(Fb + sA * 128 + cl * 4);
            a0 += bf2f(ua.x); a1 += bf2f(ua.y); a2 += bf2f(ua.z); a3 += bf2f(ua.w);
        }
        a0 += __shfl_xor(a0, 32, 64);
        a1 += __shfl_xor(a1, 32, 64);
        a2 += __shfl_xor(a2, 32, 64);
        a3 += __shfl_xor(a3, 32, 64);
        if (v < n && h == 0) {
            float inv = 1.0f / (float)(deg > 0 ? deg : 1);
            float4 r;
            r.x = a0 * inv; r.y = a1 * inv; r.z = a2 * inv; r.w = a3 * inv;
            *(float4*)&cvec[nd][128 + cl * 4] = r;
            ushort4 us = *(const ushort4*)(Fb + v * 128 + cl * 4);  // self row
            float4 sv;
            sv.x = bf2f(us.x); sv.y = bf2f(us.y); sv.z = bf2f(us.z); sv.w = bf2f(us.w);
            *(float4*)&cvec[nd][cl * 4] = sv;
        }
    }
    __syncthreads();

    // GEMM: node nd = t>>5, cols j = (t&31)*4 .. +3
    int nd = t >> 5, tn = t & 31;
    const float4* W4 = (const float4*)W0T;           // [256][32] float4
    const float4* cv4 = (const float4*)&cvec[nd][0]; // [64] float4
    float b0 = 0.f, b1 = 0.f, b2 = 0.f, b3 = 0.f;
    for (int k4 = 0; k4 < 64; ++k4) {
        float4 a = cv4[k4];
        float4 w0 = W4[(k4 * 4 + 0) * 32 + tn];
        float4 w1 = W4[(k4 * 4 + 1) * 32 + tn];
        float4 w2 = W4[(k4 * 4 + 2) * 32 + tn];
        float4 w3 = W4[(k4 * 4 + 3) * 32 + tn];
        b0 += a.x * w0.x + a.y * w1.x + a.z * w2.x + a.w * w3.x;
        b1 += a.x * w0.y + a.y * w1.y + a.z * w2.y + a.w * w3.y;
        b2 += a.x * w0.z + a.y * w1.z + a.z * w2.z + a.w * w3.z;
        b3 += a.x * w0.w + a.y * w1.w + a.z * w2.w + a.w * w3.w;
    }
    int v = vb + nd;
    if (v < n) {
        ushort4 o;
        o.x = f2bf(fmaxf(b0, 0.f));
        o.y = f2bf(fmaxf(b1, 0.f));
        o.z = f2bf(fmaxf(b2, 0.f));
        o.w = f2bf(fmaxf(b3, 0.f));
        *(ushort4*)(Hb + v * 128 + tn * 4) = o;
    }
}

// ---------- layer 2 GEMM: Z = h @ Wcat2, bf16 in/out, f32 math ----------
__global__ __launch_bounds__(256) void gemm2(const unsigned short* __restrict__ Hb,
                                             const float* __restrict__ WC,  // [128][128]
                                             unsigned short* __restrict__ Zb, int n) {
    __shared__ ushort4 Al[64][32];  // 64 rows x 128 bf16
    int t = threadIdx.x;
    int m0 = blockIdx.x * 64;
#pragma unroll
    for (int i = 0; i < 8; ++i) {
        int idx = i * 256 + t;
        int row = idx >> 5, sl = idx & 31;
        int gr = m0 + row;
        ushort4 u = {0, 0, 0, 0};
        if (gr < n) u = *(const ushort4*)(Hb + gr * 128 + sl * 4);
        Al[row][sl] = u;
    }
    __syncthreads();
    int tm = t >> 5, tn = t & 31;
    float acc[8][4];
#pragma unroll
    for (int r = 0; r < 8; ++r)
#pragma unroll
        for (int j = 0; j < 4; ++j) acc[r][j] = 0.f;
    const float4* W4 = (const float4*)WC;  // [128][32] float4
    for (int k4 = 0; k4 < 32; ++k4) {
        float4 w0 = W4[(k4 * 4 + 0) * 32 + tn];
        float4 w1 = W4[(k4 * 4 + 1) * 32 + tn];
        float4 w2 = W4[(k4 * 4 + 2) * 32 + tn];
        float4 w3 = W4[(k4 * 4 + 3) * 32 + tn];
#pragma unroll
        for (int r = 0; r < 8; ++r) {
            ushort4 u = Al[tm + r * 8][k4];
            float a0 = bf2f(u.x), a1 = bf2f(u.y), a2 = bf2f(u.z), a3 = bf2f(u.w);
            acc[r][0] += a0 * w0.x + a1 * w1.x + a2 * w2.x + a3 * w3.x;
            acc[r][1] += a0 * w0.y + a1 * w1.y + a2 * w2.y + a3 * w3.y;
            acc[r][2] += a0 * w0.z + a1 * w1.z + a2 * w2.z + a3 * w3.z;
            acc[r][3] += a0 * w0.w + a1 * w1.w + a2 * w2.w + a3 * w3.w;
        }
    }
#pragma unroll
    for (int r = 0; r < 8; ++r) {
        int row = m0 + tm + r * 8;
        if (row < n) {
            ushort4 o;
            o.x = f2bf(acc[r][0]); o.y = f2bf(acc[r][1]);
            o.z = f2bf(acc[r][2]); o.w = f2bf(acc[r][3]);
            *(ushort4*)(Zb + row * 128 + tn * 4) = o;
        }
    }
}

// ---------- layer 2 agg: out = f32(Za[v]) + mean gather Zb (64-dim bf16 rows) ----------
__global__ __launch_bounds__(256) void agg2(const unsigned short* __restrict__ Z,  // [n,128] = Za|Zb
                                            const int* __restrict__ offs,
                                            const int* __restrict__ csr,
                                            float* __restrict__ out, int n) {
    int t = threadIdx.x, lane = t & 63, wv = t >> 6;
    int slot = lane >> 4, cl = lane & 15;
    int v = blockIdx.x * 4 + wv;
    if (v >= n) return;
    int beg = offs[v], end = offs[v + 1];
    float a0 = 0.f, a1 = 0.f, a2 = 0.f, a3 = 0.f;
    int e = beg + slot;
    for (; e + 4 < end; e += 8) {  // edges e, e+4 for this 16-lane slot
        int sA = csr[e], sB = csr[e + 4];
        ushort4 ua = *(const ushort4*)(Z + sA * 128 + 64 + cl * 4);
        ushort4 ub = *(const ushort4*)(Z + sB * 128 + 64 + cl * 4);
        a0 += bf2f(ua.x) + bf2f(ub.x);
        a1 += bf2f(ua.y) + bf2f(ub.y);
        a2 += bf2f(ua.z) + bf2f(ub.z);
        a3 += bf2f(ua.w) + bf2f(ub.w);
    }
    for (; e < end; e += 4) {
        int sA = csr[e];
        ushort4 ua = *(const ushort4*)(Z + sA * 128 + 64 + cl * 4);
        a0 += bf2f(ua.x); a1 += bf2f(ua.y); a2 += bf2f(ua.z); a3 += bf2f(ua.w);
    }
    a0 += __shfl_xor(a0, 16, 64); a0 += __shfl_xor(a0, 32, 64);
    a1 += __shfl_xor(a1, 16, 64); a1 += __shfl_xor(a1, 32, 64);
    a2 += __shfl_xor(a2, 16, 64); a2 += __shfl_xor(a2, 32, 64);
    a3 += __shfl_xor(a3, 16, 64); a3 += __shfl_xor(a3, 32, 64);
    int deg = end - beg;
    float inv = 1.0f / (float)(deg > 0 ? deg : 1);
    if (slot == 0) {
        ushort4 uz = *(const ushort4*)(Z + v * 128 + cl * 4);  // Za self
        float4 o;
        o.x = bf2f(uz.x) + a0 * inv;
        o.y = bf2f(uz.y) + a1 * inv;
        o.z = bf2f(uz.z) + a2 * inv;
        o.w = bf2f(uz.w) + a3 * inv;
        *(float4*)(out + v * 64 + cl * 4) = o;
    }
}

extern "C" void kernel_launch(void* const* d_in, const int* in_sizes, int n_in,
                              void* d_out, int out_size, void* d_ws, size_t ws_size,
                              hipStream_t stream) {
    const float* feat = (const float*)d_in[0];
    const int* esrc = (const int*)d_in[1];
    const int* edst = (const int*)d_in[2];
    const float* W0 = (const float*)d_in[3];  // [128, 256]
    const float* W1 = (const float*)d_in[4];  // [64, 256]
    float* out = (float*)d_out;

    int n = in_sizes[0] / 128;  // 100000
    int E = in_sizes[1];        // 1600000

    char* ws = (char*)d_ws;
    size_t off = 0;
    auto alloc = [&](size_t bytes) -> void* {
        void* p = ws + off;
        off += (bytes + 255) & ~(size_t)255;
        return p;
    };
    int* cnt = (int*)alloc((size_t)n * 4);
    int* offs = (int*)alloc((size_t)(n + 1) * 4);
    int* pos = (int*)alloc((size_t)n * 4);
    int* csr = (int*)alloc((size_t)E * 4);
    int* partials = (int*)alloc(128 * 4);
    int* pbase = (int*)alloc(128 * 4);
    float* W0T = (float*)alloc((size_t)256 * 128 * 4);
    float* WC = (float*)alloc((size_t)128 * 128 * 4);
    unsigned short* Fb = (unsigned short*)alloc((size_t)n * 128 * 2);
    unsigned short* Hb = (unsigned short*)alloc((size_t)n * 128 * 2);
    unsigned short* Zb = Fb;  // alias: Fb dead after fused_l1, Zb born at gemm2

    int nb = (n + 1023) / 1024;  // 98

    hipMemsetAsync(cnt, 0, (size_t)n * 4, stream);
    hist_kernel<<<2048, 256, 0, stream>>>(edst, cnt, E);
    scanA<<<nb, 256, 0, stream>>>(cnt, offs, partials, n);
    scanB<<<1, 128, 0, stream>>>(partials, pbase, nb, offs + n);
    scanC<<<nb, 256, 0, stream>>>(offs, pos, pbase, n);
    scatter_kernel<<<2048, 256, 0, stream>>>(esrc, edst, pos, csr, E);
    prep_w0t<<<128, 256, 0, stream>>>(W0, W0T);
    prep_wcat2<<<64, 256, 0, stream>>>(W1, WC);
    conv_bf16<<<2048, 256, 0, stream>>>(feat, Fb, n * 32);

    fused_l1<<<(n + 7) / 8, 256, 0, stream>>>(Fb, offs, csr, W0T, Hb, n);
    gemm2<<<(n + 63) / 64, 256, 0, stream>>>(Hb, WC, Zb, n);
    agg2<<<(n + 3) / 4, 256, 0, stream>>>(Zb, offs, csr, out, n);
}

// Round 3
// 420.041 us; speedup vs baseline: 2.2355x; 1.7171x over previous
//
#include <hip/hip_runtime.h>
#include <hip/hip_bf16.h>

typedef __attribute__((ext_vector_type(8))) short bf16x8;
typedef __attribute__((ext_vector_type(4))) float f32x4;

// ---------- helpers ----------
__device__ __forceinline__ float bf2f(unsigned short u) {
    return __uint_as_float(((unsigned int)u) << 16);
}
__device__ __forceinline__ unsigned short f2bf(float f) {
    unsigned int u = __float_as_uint(f);
    unsigned int r = u + 0x7FFFu + ((u >> 16) & 1u);  // RNE
    return (unsigned short)(r >> 16);
}

// ---------- CSR build ----------
__global__ void hist_kernel(const int* __restrict__ dst, int* __restrict__ cnt, int E) {
    for (int e = blockIdx.x * blockDim.x + threadIdx.x; e < E; e += gridDim.x * blockDim.x)
        atomicAdd(&cnt[dst[e]], 1);
}

__global__ __launch_bounds__(256) void scanA(const int* __restrict__ cnt, int* __restrict__ offs,
                                             int* __restrict__ partials, int n) {
    __shared__ int wsum[4];
    __shared__ int woff[4];
    int t = threadIdx.x, lane = t & 63, wv = t >> 6;
    int i0 = blockIdx.x * 1024 + t * 4;
    int v0 = 0, v1 = 0, v2 = 0, v3 = 0;
    if (i0 + 3 < n) {
        int4 q = *(const int4*)(cnt + i0);
        v0 = q.x; v1 = q.y; v2 = q.z; v3 = q.w;
    } else {
        if (i0 < n) v0 = cnt[i0];
        if (i0 + 1 < n) v1 = cnt[i0 + 1];
        if (i0 + 2 < n) v2 = cnt[i0 + 2];
        if (i0 + 3 < n) v3 = cnt[i0 + 3];
    }
    int s0 = v0, s1 = s0 + v1, s2 = s1 + v2, s3 = s2 + v3;
    int x = s3;
#pragma unroll
    for (int o = 1; o < 64; o <<= 1) {
        int y = __shfl_up(x, o, 64);
        if (lane >= o) x += y;
    }
    if (lane == 63) wsum[wv] = x;
    __syncthreads();
    if (t == 0) {
        int r = 0;
        for (int w = 0; w < 4; ++w) { woff[w] = r; r += wsum[w]; }
        partials[blockIdx.x] = r;
    }
    __syncthreads();
    int base = woff[wv] + (x - s3);
    if (i0 < n) offs[i0] = base;
    if (i0 + 1 < n) offs[i0 + 1] = base + s0;
    if (i0 + 2 < n) offs[i0 + 2] = base + s1;
    if (i0 + 3 < n) offs[i0 + 3] = base + s2;
}

__global__ __launch_bounds__(128) void scanB(const int* __restrict__ partials, int* __restrict__ pbase,
                                             int nb, int* __restrict__ offs_n) {
    __shared__ int wsum[2];
    __shared__ int woff[2];
    int t = threadIdx.x, lane = t & 63, wv = t >> 6;
    int v = (t < nb) ? partials[t] : 0;
    int x = v;
#pragma unroll
    for (int o = 1; o < 64; o <<= 1) {
        int y = __shfl_up(x, o, 64);
        if (lane >= o) x += y;
    }
    if (lane == 63) wsum[wv] = x;
    __syncthreads();
    if (t == 0) { woff[0] = 0; woff[1] = wsum[0]; }
    __syncthreads();
    pbase[t] = woff[wv] + x - v;
    if (t == 127) *offs_n = woff[1] + x;
}

__global__ __launch_bounds__(256) void scanC(int* __restrict__ offs, int* __restrict__ pos,
                                             const int* __restrict__ pbase, int n) {
    int add = pbase[blockIdx.x];
    int i0 = blockIdx.x * 1024 + threadIdx.x * 4;
#pragma unroll
    for (int j = 0; j < 4; ++j) {
        int i = i0 + j;
        if (i < n) {
            int o = offs[i] + add;
            offs[i] = o;
            pos[i] = o;
        }
    }
}

__global__ void scatter_kernel(const int* __restrict__ src, const int* __restrict__ dst,
                               int* __restrict__ pos, int* __restrict__ csr_src, int E) {
    for (int e = blockIdx.x * blockDim.x + threadIdx.x; e < E; e += gridDim.x * blockDim.x) {
        int d = dst[e];
        int p = atomicAdd(&pos[d], 1);
        csr_src[p] = src[e];
    }
}

// ---------- conversions / weight prep ----------
__global__ void conv_bf16(const float* __restrict__ src, unsigned short* __restrict__ dst, int nquad) {
    for (int q = blockIdx.x * blockDim.x + threadIdx.x; q < nquad; q += gridDim.x * blockDim.x) {
        float4 f = *(const float4*)(src + (size_t)q * 4);
        ushort4 u;
        u.x = f2bf(f.x); u.y = f2bf(f.y); u.z = f2bf(f.z); u.w = f2bf(f.w);
        *(ushort4*)(dst + (size_t)q * 4) = u;
    }
}

// Wb1[j][k] = bf16(W0[j][k])  (identical layout, 128x256)
__global__ void conv_w0(const float* __restrict__ W0, unsigned short* __restrict__ Wb1) {
    int i = blockIdx.x * 256 + threadIdx.x;  // 32768
    Wb1[i] = f2bf(W0[i]);
}
// Wb2[j][k], j,k in [0,128): j<64 -> W1[j][k] ; j>=64 -> W1[j-64][128+k]
__global__ void conv_w1(const float* __restrict__ W1, unsigned short* __restrict__ Wb2) {
    int i = blockIdx.x * 256 + threadIdx.x;  // 16384
    int j = i >> 7, k = i & 127;
    float v = (j < 64) ? W1[j * 256 + k] : W1[(j - 64) * 256 + 128 + k];
    Wb2[i] = f2bf(v);
}

// ---------- agg1: Mb[v] = mean_{u in N(v)} Fb[u]  (128-dim bf16 rows) ----------
// one wave per node; lane covers elems 2l,2l+1; 4 edges in flight
__global__ __launch_bounds__(256) void agg1(const unsigned short* __restrict__ Fb,
                                            const int* __restrict__ offs,
                                            const int* __restrict__ csr,
                                            unsigned short* __restrict__ Mb, int n) {
    int t = threadIdx.x, l = t & 63, wv = t >> 6;
    int v = blockIdx.x * 4 + wv;
    if (v >= n) return;
    int beg = offs[v], end = offs[v + 1];
    float a0 = 0.f, a1 = 0.f;
    int e = beg;
    for (; e + 3 < end; e += 4) {
        int s0 = csr[e], s1 = csr[e + 1], s2 = csr[e + 2], s3 = csr[e + 3];
        unsigned int r0 = *(const unsigned int*)(Fb + (size_t)s0 * 128 + l * 2);
        unsigned int r1 = *(const unsigned int*)(Fb + (size_t)s1 * 128 + l * 2);
        unsigned int r2 = *(const unsigned int*)(Fb + (size_t)s2 * 128 + l * 2);
        unsigned int r3 = *(const unsigned int*)(Fb + (size_t)s3 * 128 + l * 2);
        a0 += bf2f((unsigned short)r0) + bf2f((unsigned short)r1) +
              bf2f((unsigned short)r2) + bf2f((unsigned short)r3);
        a1 += bf2f((unsigned short)(r0 >> 16)) + bf2f((unsigned short)(r1 >> 16)) +
              bf2f((unsigned short)(r2 >> 16)) + bf2f((unsigned short)(r3 >> 16));
    }
    for (; e < end; ++e) {
        int s0 = csr[e];
        unsigned int r0 = *(const unsigned int*)(Fb + (size_t)s0 * 128 + l * 2);
        a0 += bf2f((unsigned short)r0);
        a1 += bf2f((unsigned short)(r0 >> 16));
    }
    int deg = end - beg;
    float inv = 1.0f / (float)(deg > 0 ? deg : 1);
    unsigned int o = (unsigned int)f2bf(a0 * inv) | ((unsigned int)f2bf(a1 * inv) << 16);
    *(unsigned int*)(Mb + (size_t)v * 128 + l * 2) = o;
}

// ---------- MFMA GEMM: Out[n,128] = A[n,K] @ Wb[128,K]^T (bf16 in/out, f32 acc) ----------
// A row: k<128 from PA, k>=128 from PB (both [n][128]). Block = 128 rows, 4 waves,
// wave w -> rows w*32..w*32+31 (2 m-frags x 8 n-frags of 16x16x32).
template <int K, bool RELU>
__global__ __launch_bounds__(256) void mfma_gemm(const unsigned short* __restrict__ PA,
                                                 const unsigned short* __restrict__ PB,
                                                 const unsigned short* __restrict__ Wb,  // [128][K]
                                                 unsigned short* __restrict__ Out,
                                                 int n) {
    __shared__ unsigned short ctile[128][128];
    int t = threadIdx.x, l = t & 63, w = t >> 6;
    int m0 = blockIdx.x * 128;
    int lr = l & 15;          // row/col within fragment
    int lk = (l >> 4) * 8;    // k-offset within 32-chunk

    f32x4 acc[2][8];
#pragma unroll
    for (int m = 0; m < 2; ++m)
#pragma unroll
        for (int nf = 0; nf < 8; ++nf) acc[m][nf] = (f32x4){0.f, 0.f, 0.f, 0.f};

#pragma unroll
    for (int kc = 0; kc < K / 32; ++kc) {
        int kb = kc * 32 + lk;
        const unsigned short* src = (K == 256 && kb >= 128) ? PB : PA;
        int kcol = kb & 127;
        bf16x8 a[2];
#pragma unroll
        for (int m = 0; m < 2; ++m) {
            int row = m0 + w * 32 + m * 16 + lr;
            row = (row < n) ? row : (n - 1);
            a[m] = *(const bf16x8*)(src + (size_t)row * 128 + kcol);
        }
        bf16x8 b[8];
#pragma unroll
        for (int nf = 0; nf < 8; ++nf)
            b[nf] = *(const bf16x8*)(Wb + (size_t)(nf * 16 + lr) * K + kb);
#pragma unroll
        for (int m = 0; m < 2; ++m)
#pragma unroll
            for (int nf = 0; nf < 8; ++nf)
                acc[m][nf] = __builtin_amdgcn_mfma_f32_16x16x32_bf16(a[m], b[nf], acc[m][nf], 0, 0, 0);
    }

    // acc -> LDS (C/D layout: col = l&15, row = (l>>4)*4 + r)
    int rbase = (l >> 4) * 4;
#pragma unroll
    for (int m = 0; m < 2; ++m)
#pragma unroll
        for (int nf = 0; nf < 8; ++nf)
#pragma unroll
            for (int r = 0; r < 4; ++r) {
                float vv = acc[m][nf][r];
                if (RELU) vv = fmaxf(vv, 0.f);
                ctile[w * 32 + m * 16 + rbase + r][nf * 16 + lr] = f2bf(vv);
            }
    __syncthreads();

    // coalesced store: 2048 ushort8 chunks, 8 per thread
#pragma unroll
    for (int c = 0; c < 8; ++c) {
        int chunk = c * 256 + t;
        int row = chunk >> 4, col8 = (chunk & 15) * 8;
        int grow = m0 + row;
        if (grow < n)
            *(bf16x8*)(Out + (size_t)grow * 128 + col8) = *(const bf16x8*)&ctile[row][col8];
    }
}

// ---------- agg2: out[v][c] = f32(Z[v][c]) + mean_{u} Z[u][64+c]  (c in [0,64)) ----------
__global__ __launch_bounds__(256) void agg2(const unsigned short* __restrict__ Z,
                                            const int* __restrict__ offs,
                                            const int* __restrict__ csr,
                                            float* __restrict__ out, int n) {
    int t = threadIdx.x, l = t & 63, wv = t >> 6;
    int h = l >> 5, cl = l & 31;
    int v = blockIdx.x * 4 + wv;
    if (v >= n) return;
    int beg = offs[v], end = offs[v + 1];
    float a0 = 0.f, a1 = 0.f;
    int e = beg + h;
    for (; e + 2 < end; e += 4) {  // this half-wave: e, e+2
        int s0 = csr[e], s1 = csr[e + 2];
        unsigned int r0 = *(const unsigned int*)(Z + (size_t)s0 * 128 + 64 + cl * 2);
        unsigned int r1 = *(const unsigned int*)(Z + (size_t)s1 * 128 + 64 + cl * 2);
        a0 += bf2f((unsigned short)r0) + bf2f((unsigned short)r1);
        a1 += bf2f((unsigned short)(r0 >> 16)) + bf2f((unsigned short)(r1 >> 16));
    }
    for (; e < end; e += 2) {
        int s0 = csr[e];
        unsigned int r0 = *(const unsigned int*)(Z + (size_t)s0 * 128 + 64 + cl * 2);
        a0 += bf2f((unsigned short)r0);
        a1 += bf2f((unsigned short)(r0 >> 16));
    }
    a0 += __shfl_xor(a0, 32, 64);
    a1 += __shfl_xor(a1, 32, 64);
    int deg = end - beg;
    float inv = 1.0f / (float)(deg > 0 ? deg : 1);
    if (h == 0) {
        unsigned int uz = *(const unsigned int*)(Z + (size_t)v * 128 + cl * 2);
        float2 o;
        o.x = bf2f((unsigned short)uz) + a0 * inv;
        o.y = bf2f((unsigned short)(uz >> 16)) + a1 * inv;
        *(float2*)(out + (size_t)v * 64 + cl * 2) = o;
    }
}

extern "C" void kernel_launch(void* const* d_in, const int* in_sizes, int n_in,
                              void* d_out, int out_size, void* d_ws, size_t ws_size,
                              hipStream_t stream) {
    const float* feat = (const float*)d_in[0];
    const int* esrc = (const int*)d_in[1];
    const int* edst = (const int*)d_in[2];
    const float* W0 = (const float*)d_in[3];  // [128, 256]
    const float* W1 = (const float*)d_in[4];  // [64, 256]
    float* out = (float*)d_out;

    int n = in_sizes[0] / 128;  // 100000
    int E = in_sizes[1];        // 1600000

    char* ws = (char*)d_ws;
    size_t off = 0;
    auto alloc = [&](size_t bytes) -> void* {
        void* p = ws + off;
        off += (bytes + 255) & ~(size_t)255;
        return p;
    };
    int* cnt = (int*)alloc((size_t)n * 4);
    int* offs = (int*)alloc((size_t)(n + 1) * 4);
    int* pos = (int*)alloc((size_t)n * 4);
    int* csr = (int*)alloc((size_t)E * 4);
    int* partials = (int*)alloc(128 * 4);
    int* pbase = (int*)alloc(128 * 4);
    unsigned short* Wb1 = (unsigned short*)alloc((size_t)128 * 256 * 2);
    unsigned short* Wb2 = (unsigned short*)alloc((size_t)128 * 128 * 2);
    unsigned short* Fb = (unsigned short*)alloc((size_t)n * 128 * 2);
    unsigned short* Mb = (unsigned short*)alloc((size_t)n * 128 * 2);
    unsigned short* Hb = (unsigned short*)alloc((size_t)n * 128 * 2);
    unsigned short* Z = Fb;  // Fb dead after gemm1; reuse for Z

    int nb = (n + 1023) / 1024;  // 98

    hipMemsetAsync(cnt, 0, (size_t)n * 4, stream);
    hist_kernel<<<2048, 256, 0, stream>>>(edst, cnt, E);
    scanA<<<nb, 256, 0, stream>>>(cnt, offs, partials, n);
    scanB<<<1, 128, 0, stream>>>(partials, pbase, nb, offs + n);
    scanC<<<nb, 256, 0, stream>>>(offs, pos, pbase, n);
    scatter_kernel<<<2048, 256, 0, stream>>>(esrc, edst, pos, csr, E);
    conv_bf16<<<2048, 256, 0, stream>>>(feat, Fb, n * 32);
    conv_w0<<<128, 256, 0, stream>>>(W0, Wb1);
    conv_w1<<<64, 256, 0, stream>>>(W1, Wb2);

    agg1<<<(n + 3) / 4, 256, 0, stream>>>(Fb, offs, csr, Mb, n);
    mfma_gemm<256, true><<<(n + 127) / 128, 256, 0, stream>>>(Fb, Mb, Wb1, Hb, n);
    mfma_gemm<128, false><<<(n + 127) / 128, 256, 0, stream>>>(Hb, Hb, Wb2, Z, n);
    agg2<<<(n + 3) / 4, 256, 0, stream>>>(Z, offs, csr, out, n);
}

// Round 4
// 261.680 us; speedup vs baseline: 3.5884x; 1.6052x over previous
//
#include <hip/hip_runtime.h>
#include <hip/hip_bf16.h>

typedef __attribute__((ext_vector_type(8))) short bf16x8;
typedef __attribute__((ext_vector_type(4))) float f32x4;

#define BSH 9              // nodes per bucket = 512
#define BCAP 12288         // per-bucket pair capacity (mean 8163, std ~90 -> 45 sigma)

// ---------- helpers ----------
__device__ __forceinline__ float bf2f(unsigned short u) {
    return __uint_as_float(((unsigned int)u) << 16);
}
__device__ __forceinline__ unsigned short f2bf(float f) {
    unsigned int u = __float_as_uint(f);
    unsigned int r = u + 0x7FFFu + ((u >> 16) & 1u);  // RNE
    return (unsigned short)(r >> 16);
}

// ---------- CSR build: two-level bucketed counting sort ----------
__global__ void init_gcur(int* __restrict__ gcur, int NB) {
    int b = blockIdx.x * blockDim.x + threadIdx.x;
    if (b < NB) gcur[b] = b * BCAP;
}

// phase 1: partition edges into buckets of 512 dst-nodes, packed (src | dlow<<17)
// requires n <= 131072 (17-bit src), NB <= 256
__global__ __launch_bounds__(256) void partition(const int* __restrict__ esrc,
                                                 const int* __restrict__ edst,
                                                 int* __restrict__ gcur,
                                                 unsigned int* __restrict__ pairs,
                                                 int E, int NB) {
    __shared__ int bcnt[256];
    __shared__ int bbas[256];
    int t = threadIdx.x;
    int e0 = blockIdx.x * 4096;
    int eend = min(e0 + 4096, E);
    if (t < NB) bcnt[t] = 0;
    __syncthreads();
    for (int e = e0 + t; e < eend; e += 256) atomicAdd(&bcnt[edst[e] >> BSH], 1);
    __syncthreads();
    if (t < NB) {
        bbas[t] = atomicAdd(&gcur[t], bcnt[t]);
        bcnt[t] = 0;  // reuse as block-local cursor
    }
    __syncthreads();
    for (int e = e0 + t; e < eend; e += 256) {
        int d = edst[e];
        int s = esrc[e];
        int b = d >> BSH;
        int off = atomicAdd(&bcnt[b], 1);
        pairs[bbas[b] + off] = (unsigned int)s | ((unsigned int)(d & ((1 << BSH) - 1)) << 17);
    }
}

// scan of NB bucket counts -> bbase[0..NB]; also offs[n] = E
__global__ __launch_bounds__(256) void bscan(const int* __restrict__ gcur, int* __restrict__ bbase,
                                             int* __restrict__ offs, int n, int NB, int E) {
    __shared__ int wsum[4];
    __shared__ int woff[4];
    int t = threadIdx.x, lane = t & 63, wv = t >> 6;
    int v = (t < NB) ? (gcur[t] - t * BCAP) : 0;
    int x = v;
#pragma unroll
    for (int o = 1; o < 64; o <<= 1) {
        int y = __shfl_up(x, o, 64);
        if (lane >= o) x += y;
    }
    if (lane == 63) wsum[wv] = x;
    __syncthreads();
    if (t == 0) {
        int r = 0;
        for (int w = 0; w < 4; ++w) { woff[w] = r; r += wsum[w]; }
    }
    __syncthreads();
    int e = woff[wv] + x - v;
    if (t < NB) bbase[t] = e;
    if (t == NB - 1) bbase[NB] = e + v;
    if (t == 0) offs[n] = E;
}

// phase 2: per-bucket block -> per-node offsets (coalesced) + csr placement (L2-local random)
__global__ __launch_bounds__(256) void build(const unsigned int* __restrict__ pairs,
                                             const int* __restrict__ gcur,
                                             const int* __restrict__ bbase,
                                             int* __restrict__ offs, int* __restrict__ csr,
                                             int n) {
    __shared__ int cnt[512];
    __shared__ int excl[512];
    __shared__ int wsum[4];
    __shared__ int woff[4];
    int b = blockIdx.x, t = threadIdx.x, lane = t & 63, wv = t >> 6;
    int p0 = b * BCAP;
    int m = gcur[b] - p0;
    int base = bbase[b];
    int v0 = b << BSH;
    cnt[t] = 0;
    cnt[t + 256] = 0;
    __syncthreads();
    for (int i = t; i < m; i += 256) atomicAdd(&cnt[pairs[p0 + i] >> 17], 1);
    __syncthreads();
    int c0 = cnt[2 * t], c1 = cnt[2 * t + 1];
    int s = c0 + c1;
    int x = s;
#pragma unroll
    for (int o = 1; o < 64; o <<= 1) {
        int y = __shfl_up(x, o, 64);
        if (lane >= o) x += y;
    }
    if (lane == 63) wsum[wv] = x;
    __syncthreads();
    if (t == 0) {
        int r = 0;
        for (int w = 0; w < 4; ++w) { woff[w] = r; r += wsum[w]; }
    }
    __syncthreads();
    int ex = woff[wv] + x - s;
    excl[2 * t] = ex;
    excl[2 * t + 1] = ex + c0;
    int v = v0 + 2 * t;
    if (v + 1 < n) {
        int2 o2;
        o2.x = base + ex;
        o2.y = base + ex + c0;
        *(int2*)(offs + v) = o2;
    } else if (v < n) {
        offs[v] = base + ex;
    }
    cnt[t] = 0;
    cnt[t + 256] = 0;
    __syncthreads();
    for (int i = t; i < m; i += 256) {
        unsigned int u = pairs[p0 + i];
        int dl = u >> 17;
        int off = atomicAdd(&cnt[dl], 1);
        csr[base + excl[dl] + off] = (int)(u & 0x1FFFFu);
    }
}

// ---------- conversions / weight prep ----------
__global__ void conv_bf16(const float* __restrict__ src, unsigned short* __restrict__ dst, int nquad) {
    for (int q = blockIdx.x * blockDim.x + threadIdx.x; q < nquad; q += gridDim.x * blockDim.x) {
        float4 f = *(const float4*)(src + (size_t)q * 4);
        ushort4 u;
        u.x = f2bf(f.x); u.y = f2bf(f.y); u.z = f2bf(f.z); u.w = f2bf(f.w);
        *(ushort4*)(dst + (size_t)q * 4) = u;
    }
}

__global__ void conv_w0(const float* __restrict__ W0, unsigned short* __restrict__ Wb1) {
    int i = blockIdx.x * 256 + threadIdx.x;  // 32768
    Wb1[i] = f2bf(W0[i]);
}
__global__ void conv_w1(const float* __restrict__ W1, unsigned short* __restrict__ Wb2) {
    int i = blockIdx.x * 256 + threadIdx.x;  // 16384
    int j = i >> 7, k = i & 127;
    float v = (j < 64) ? W1[j * 256 + k] : W1[(j - 64) * 256 + 128 + k];
    Wb2[i] = f2bf(v);
}

// ---------- agg1: Mb[v] = mean_{u in N(v)} Fb[u]  (128-dim bf16 rows) ----------
__global__ __launch_bounds__(256) void agg1(const unsigned short* __restrict__ Fb,
                                            const int* __restrict__ offs,
                                            const int* __restrict__ csr,
                                            unsigned short* __restrict__ Mb, int n) {
    int t = threadIdx.x, l = t & 63, wv = t >> 6;
    int v = blockIdx.x * 4 + wv;
    if (v >= n) return;
    int beg = offs[v], end = offs[v + 1];
    float a0 = 0.f, a1 = 0.f;
    int e = beg;
    for (; e + 3 < end; e += 4) {
        int s0 = csr[e], s1 = csr[e + 1], s2 = csr[e + 2], s3 = csr[e + 3];
        unsigned int r0 = *(const unsigned int*)(Fb + (size_t)s0 * 128 + l * 2);
        unsigned int r1 = *(const unsigned int*)(Fb + (size_t)s1 * 128 + l * 2);
        unsigned int r2 = *(const unsigned int*)(Fb + (size_t)s2 * 128 + l * 2);
        unsigned int r3 = *(const unsigned int*)(Fb + (size_t)s3 * 128 + l * 2);
        a0 += bf2f((unsigned short)r0) + bf2f((unsigned short)r1) +
              bf2f((unsigned short)r2) + bf2f((unsigned short)r3);
        a1 += bf2f((unsigned short)(r0 >> 16)) + bf2f((unsigned short)(r1 >> 16)) +
              bf2f((unsigned short)(r2 >> 16)) + bf2f((unsigned short)(r3 >> 16));
    }
    for (; e < end; ++e) {
        int s0 = csr[e];
        unsigned int r0 = *(const unsigned int*)(Fb + (size_t)s0 * 128 + l * 2);
        a0 += bf2f((unsigned short)r0);
        a1 += bf2f((unsigned short)(r0 >> 16));
    }
    int deg = end - beg;
    float inv = 1.0f / (float)(deg > 0 ? deg : 1);
    unsigned int o = (unsigned int)f2bf(a0 * inv) | ((unsigned int)f2bf(a1 * inv) << 16);
    *(unsigned int*)(Mb + (size_t)v * 128 + l * 2) = o;
}

// ---------- MFMA GEMM: Out[n,128] = A[n,K] @ Wb[128,K]^T ----------
template <int K, bool RELU>
__global__ __launch_bounds__(256) void mfma_gemm(const unsigned short* __restrict__ PA,
                                                 const unsigned short* __restrict__ PB,
                                                 const unsigned short* __restrict__ Wb,  // [128][K]
                                                 unsigned short* __restrict__ Out,
                                                 int n) {
    __shared__ unsigned short ctile[128][128];
    int t = threadIdx.x, l = t & 63, w = t >> 6;
    int m0 = blockIdx.x * 128;
    int lr = l & 15;
    int lk = (l >> 4) * 8;

    f32x4 acc[2][8];
#pragma unroll
    for (int m = 0; m < 2; ++m)
#pragma unroll
        for (int nf = 0; nf < 8; ++nf) acc[m][nf] = (f32x4){0.f, 0.f, 0.f, 0.f};

#pragma unroll
    for (int kc = 0; kc < K / 32; ++kc) {
        int kb = kc * 32 + lk;
        const unsigned short* src = (K == 256 && kb >= 128) ? PB : PA;
        int kcol = kb & 127;
        bf16x8 a[2];
#pragma unroll
        for (int m = 0; m < 2; ++m) {
            int row = m0 + w * 32 + m * 16 + lr;
            row = (row < n) ? row : (n - 1);
            a[m] = *(const bf16x8*)(src + (size_t)row * 128 + kcol);
        }
        bf16x8 b[8];
#pragma unroll
        for (int nf = 0; nf < 8; ++nf)
            b[nf] = *(const bf16x8*)(Wb + (size_t)(nf * 16 + lr) * K + kb);
#pragma unroll
        for (int m = 0; m < 2; ++m)
#pragma unroll
            for (int nf = 0; nf < 8; ++nf)
                acc[m][nf] = __builtin_amdgcn_mfma_f32_16x16x32_bf16(a[m], b[nf], acc[m][nf], 0, 0, 0);
    }

    int rbase = (l >> 4) * 4;
#pragma unroll
    for (int m = 0; m < 2; ++m)
#pragma unroll
        for (int nf = 0; nf < 8; ++nf)
#pragma unroll
            for (int r = 0; r < 4; ++r) {
                float vv = acc[m][nf][r];
                if (RELU) vv = fmaxf(vv, 0.f);
                ctile[w * 32 + m * 16 + rbase + r][nf * 16 + lr] = f2bf(vv);
            }
    __syncthreads();

#pragma unroll
    for (int c = 0; c < 8; ++c) {
        int chunk = c * 256 + t;
        int row = chunk >> 4, col8 = (chunk & 15) * 8;
        int grow = m0 + row;
        if (grow < n)
            *(bf16x8*)(Out + (size_t)grow * 128 + col8) = *(const bf16x8*)&ctile[row][col8];
    }
}

// ---------- agg2: out[v][c] = f32(Z[v][c]) + mean_{u} Z[u][64+c] ----------
__global__ __launch_bounds__(256) void agg2(const unsigned short* __restrict__ Z,
                                            const int* __restrict__ offs,
                                            const int* __restrict__ csr,
                                            float* __restrict__ out, int n) {
    int t = threadIdx.x, l = t & 63, wv = t >> 6;
    int h = l >> 5, cl = l & 31;
    int v = blockIdx.x * 4 + wv;
    if (v >= n) return;
    int beg = offs[v], end = offs[v + 1];
    float a0 = 0.f, a1 = 0.f;
    int e = beg + h;
    for (; e + 2 < end; e += 4) {
        int s0 = csr[e], s1 = csr[e + 2];
        unsigned int r0 = *(const unsigned int*)(Z + (size_t)s0 * 128 + 64 + cl * 2);
        unsigned int r1 = *(const unsigned int*)(Z + (size_t)s1 * 128 + 64 + cl * 2);
        a0 += bf2f((unsigned short)r0) + bf2f((unsigned short)r1);
        a1 += bf2f((unsigned short)(r0 >> 16)) + bf2f((unsigned short)(r1 >> 16));
    }
    for (; e < end; e += 2) {
        int s0 = csr[e];
        unsigned int r0 = *(const unsigned int*)(Z + (size_t)s0 * 128 + 64 + cl * 2);
        a0 += bf2f((unsigned short)r0);
        a1 += bf2f((unsigned short)(r0 >> 16));
    }
    a0 += __shfl_xor(a0, 32, 64);
    a1 += __shfl_xor(a1, 32, 64);
    int deg = end - beg;
    float inv = 1.0f / (float)(deg > 0 ? deg : 1);
    if (h == 0) {
        unsigned int uz = *(const unsigned int*)(Z + (size_t)v * 128 + cl * 2);
        float2 o;
        o.x = bf2f((unsigned short)uz) + a0 * inv;
        o.y = bf2f((unsigned short)(uz >> 16)) + a1 * inv;
        *(float2*)(out + (size_t)v * 64 + cl * 2) = o;
    }
}

extern "C" void kernel_launch(void* const* d_in, const int* in_sizes, int n_in,
                              void* d_out, int out_size, void* d_ws, size_t ws_size,
                              hipStream_t stream) {
    const float* feat = (const float*)d_in[0];
    const int* esrc = (const int*)d_in[1];
    const int* edst = (const int*)d_in[2];
    const float* W0 = (const float*)d_in[3];  // [128, 256]
    const float* W1 = (const float*)d_in[4];  // [64, 256]
    float* out = (float*)d_out;

    int n = in_sizes[0] / 128;  // 100000
    int E = in_sizes[1];        // 1600000
    int NB = (n + 511) >> 9;    // 196 buckets

    char* ws = (char*)d_ws;
    size_t off = 0;
    auto alloc = [&](size_t bytes) -> void* {
        void* p = ws + off;
        off += (bytes + 255) & ~(size_t)255;
        return p;
    };
    int* offs = (int*)alloc((size_t)(n + 1) * 4);
    int* csr = (int*)alloc((size_t)E * 4);
    int* gcur = (int*)alloc((size_t)NB * 4);
    int* bbase = (int*)alloc((size_t)(NB + 1) * 4);
    unsigned short* Wb1 = (unsigned short*)alloc((size_t)128 * 256 * 2);
    unsigned short* Wb2 = (unsigned short*)alloc((size_t)128 * 128 * 2);
    unsigned short* Fb = (unsigned short*)alloc((size_t)n * 128 * 2);
    unsigned short* Mb = (unsigned short*)alloc((size_t)n * 128 * 2);
    unsigned short* Hb = (unsigned short*)alloc((size_t)n * 128 * 2);
    unsigned short* Z = Fb;                   // Fb dead after gemm1
    unsigned int* pairs = (unsigned int*)Hb;  // pairs dead before Hb is written (NB*BCAP*4 = 9.6 MB < 25.6 MB)

    init_gcur<<<(NB + 255) / 256, 256, 0, stream>>>(gcur, NB);
    partition<<<(E + 4095) / 4096, 256, 0, stream>>>(esrc, edst, gcur, pairs, E, NB);
    bscan<<<1, 256, 0, stream>>>(gcur, bbase, offs, n, NB, E);
    build<<<NB, 256, 0, stream>>>(pairs, gcur, bbase, offs, csr, n);

    conv_bf16<<<2048, 256, 0, stream>>>(feat, Fb, n * 32);
    conv_w0<<<128, 256, 0, stream>>>(W0, Wb1);
    conv_w1<<<64, 256, 0, stream>>>(W1, Wb2);

    agg1<<<(n + 3) / 4, 256, 0, stream>>>(Fb, offs, csr, Mb, n);
    mfma_gemm<256, true><<<(n + 127) / 128, 256, 0, stream>>>(Fb, Mb, Wb1, Hb, n);
    mfma_gemm<128, false><<<(n + 127) / 128, 256, 0, stream>>>(Hb, Hb, Wb2, Z, n);
    agg2<<<(n + 3) / 4, 256, 0, stream>>>(Z, offs, csr, out, n);
}

// Round 5
// 229.529 us; speedup vs baseline: 4.0910x; 1.1401x over previous
//
#include <hip/hip_runtime.h>
#include <hip/hip_bf16.h>

typedef __attribute__((ext_vector_type(8))) short bf16x8;
typedef __attribute__((ext_vector_type(4))) float f32x4;
typedef __attribute__((ext_vector_type(2))) float f32x2;

#define BSH 9       // nodes per bucket = 512
#define BCAP 12288  // per-bucket pair capacity (mean 8163, std ~90)

#if __has_builtin(__builtin_amdgcn_cvt_pk_f32_fp8) && __has_builtin(__builtin_amdgcn_cvt_pk_fp8_f32)
#define FP8_HW 1
#else
#define FP8_HW 0
#endif

// ---------- helpers ----------
__device__ __forceinline__ float bf2f(unsigned short u) {
    return __uint_as_float(((unsigned int)u) << 16);
}
__device__ __forceinline__ unsigned short f2bf(float f) {
    unsigned int u = __float_as_uint(f);
    unsigned int r = u + 0x7FFFu + ((u >> 16) & 1u);  // RNE
    return (unsigned short)(r >> 16);
}

#if !FP8_HW
// manual OCP e4m3 encode/decode fallbacks
__device__ __forceinline__ unsigned int f2fp8_sw(float v) {
    unsigned int u = __float_as_uint(v);
    unsigned int s = (u >> 24) & 0x80u;
    unsigned int a = u & 0x7FFFFFFFu;
    float av = __uint_as_float(a);
    unsigned int q;
    if (av >= 0.015625f) {  // normal (>= 2^-6)
        unsigned int r = a + 0x7FFFFu + ((a >> 20) & 1u);
        q = (r - (120u << 23)) >> 20;
        if (q > 0x7Eu) q = 0x7Eu;  // clamp to 448
    } else {
        q = (unsigned int)(av * 512.0f + 0.5f);  // subnormal
    }
    return s | q;
}
__device__ __forceinline__ float fp8_dec_sw(unsigned int u8) {
    unsigned int s = (u8 & 0x80u) << 24;
    unsigned int em = u8 & 0x7Fu;
    float vn = __uint_as_float(s | ((em << 20) + (120u << 23)));
    float vs = __uint_as_float(s | 0x3B000000u) * (float)(int)em;  // ±2^-9 * mant
    return em >= 8 ? vn : vs;
}
#endif

__device__ __forceinline__ void fp8x2_dec(unsigned int u16, float& x, float& y) {
#if FP8_HW
    f32x2 r = __builtin_amdgcn_cvt_pk_f32_fp8((int)u16, false);
    x = r.x;
    y = r.y;
#else
    x = fp8_dec_sw(u16 & 0xFFu);
    y = fp8_dec_sw((u16 >> 8) & 0xFFu);
#endif
}
__device__ __forceinline__ unsigned int fp8x4_enc(float a, float b, float c, float d) {
#if FP8_HW
    int u = __builtin_amdgcn_cvt_pk_fp8_f32(a, b, 0, false);
    u = __builtin_amdgcn_cvt_pk_fp8_f32(c, d, u, true);
    return (unsigned int)u;
#else
    return f2fp8_sw(a) | (f2fp8_sw(b) << 8) | (f2fp8_sw(c) << 16) | (f2fp8_sw(d) << 24);
#endif
}
__device__ __forceinline__ unsigned char fp8_enc1(float a) {
#if FP8_HW
    return (unsigned char)(__builtin_amdgcn_cvt_pk_fp8_f32(a, a, 0, false) & 0xFF);
#else
    return (unsigned char)f2fp8_sw(a);
#endif
}

// ---------- megaA: partition (blocks [0,pb)) + feat conv (bf16+fp8) + weight conv ----------
__global__ __launch_bounds__(256) void megaA(const int* __restrict__ esrc, const int* __restrict__ edst,
                                             int* __restrict__ gcur, unsigned int* __restrict__ pairs,
                                             int E, int NB,
                                             const float* __restrict__ feat, unsigned short* __restrict__ Fb,
                                             unsigned char* __restrict__ Ff8, int nquad,
                                             const float* __restrict__ W0, unsigned short* __restrict__ Wb1,
                                             const float* __restrict__ W1, unsigned short* __restrict__ Wb2,
                                             int pblocks, int cblocks) {
    __shared__ int bcnt[256];
    __shared__ int bbas[256];
    int b = blockIdx.x, t = threadIdx.x;
    if (b < pblocks) {
        int e0 = b * 4096;
        int eend = min(e0 + 4096, E);
        if (t < NB) bcnt[t] = 0;
        __syncthreads();
        for (int e = e0 + t; e < eend; e += 256) atomicAdd(&bcnt[edst[e] >> BSH], 1);
        __syncthreads();
        if (t < NB) {
            bbas[t] = t * BCAP + atomicAdd(&gcur[t], bcnt[t]);
            bcnt[t] = 0;  // reuse as block-local cursor
        }
        __syncthreads();
        for (int e = e0 + t; e < eend; e += 256) {
            int d = edst[e];
            int s = esrc[e];
            int bk = d >> BSH;
            int off = atomicAdd(&bcnt[bk], 1);
            pairs[bbas[bk] + off] = (unsigned int)s | ((unsigned int)(d & ((1 << BSH) - 1)) << 17);
        }
    } else if (b < pblocks + cblocks) {
        int cb = b - pblocks;
        for (int q = cb * 256 + t; q < nquad; q += cblocks * 256) {
            float4 f = *(const float4*)(feat + (size_t)q * 4);
            ushort4 ub;
            ub.x = f2bf(f.x); ub.y = f2bf(f.y); ub.z = f2bf(f.z); ub.w = f2bf(f.w);
            *(ushort4*)(Fb + (size_t)q * 4) = ub;
            *(unsigned int*)(Ff8 + (size_t)q * 4) = fp8x4_enc(f.x, f.y, f.z, f.w);
        }
    } else {
        int wb = b - pblocks - cblocks;
        for (int i = wb * 256 + t; i < 49152; i += 24 * 256) {
            if (i < 32768) {
                Wb1[i] = f2bf(W0[i]);
            } else {
                int i2 = i - 32768;
                int j = i2 >> 7, k = i2 & 127;
                float vv = (j < 64) ? W1[j * 256 + k] : W1[(j - 64) * 256 + 128 + k];
                Wb2[i2] = f2bf(vv);
            }
        }
    }
}

// ---------- bscan: prefix of bucket counts ----------
__global__ __launch_bounds__(256) void bscan(const int* __restrict__ gcur, int* __restrict__ bbase,
                                             int* __restrict__ offs, int n, int NB, int E) {
    __shared__ int wsum[4];
    __shared__ int woff[4];
    int t = threadIdx.x, lane = t & 63, wv = t >> 6;
    int v = (t < NB) ? gcur[t] : 0;
    int x = v;
#pragma unroll
    for (int o = 1; o < 64; o <<= 1) {
        int y = __shfl_up(x, o, 64);
        if (lane >= o) x += y;
    }
    if (lane == 63) wsum[wv] = x;
    __syncthreads();
    if (t == 0) {
        int r = 0;
        for (int w = 0; w < 4; ++w) { woff[w] = r; r += wsum[w]; }
    }
    __syncthreads();
    int e = woff[wv] + x - v;
    if (t < NB) bbase[t] = e;
    if (t == NB - 1) bbase[NB] = e + v;
    if (t == 0) offs[n] = E;
}

// ---------- build: per-bucket offsets + csr placement ----------
__global__ __launch_bounds__(256) void build(const unsigned int* __restrict__ pairs,
                                             const int* __restrict__ gcur,
                                             const int* __restrict__ bbase,
                                             int* __restrict__ offs, int* __restrict__ csr,
                                             int n) {
    __shared__ int cnt[512];
    __shared__ int excl[512];
    __shared__ int wsum[4];
    __shared__ int woff[4];
    int b = blockIdx.x, t = threadIdx.x, lane = t & 63, wv = t >> 6;
    int p0 = b * BCAP;
    int m = gcur[b];
    int base = bbase[b];
    int v0 = b << BSH;
    cnt[t] = 0;
    cnt[t + 256] = 0;
    __syncthreads();
    for (int i = t; i < m; i += 256) atomicAdd(&cnt[pairs[p0 + i] >> 17], 1);
    __syncthreads();
    int c0 = cnt[2 * t], c1 = cnt[2 * t + 1];
    int s = c0 + c1;
    int x = s;
#pragma unroll
    for (int o = 1; o < 64; o <<= 1) {
        int y = __shfl_up(x, o, 64);
        if (lane >= o) x += y;
    }
    if (lane == 63) wsum[wv] = x;
    __syncthreads();
    if (t == 0) {
        int r = 0;
        for (int w = 0; w < 4; ++w) { woff[w] = r; r += wsum[w]; }
    }
    __syncthreads();
    int ex = woff[wv] + x - s;
    excl[2 * t] = ex;
    excl[2 * t + 1] = ex + c0;
    int v = v0 + 2 * t;
    if (v + 1 < n) {
        int2 o2;
        o2.x = base + ex;
        o2.y = base + ex + c0;
        *(int2*)(offs + v) = o2;
    } else if (v < n) {
        offs[v] = base + ex;
    }
    cnt[t] = 0;
    cnt[t + 256] = 0;
    __syncthreads();
    for (int i = t; i < m; i += 256) {
        unsigned int u = pairs[p0 + i];
        int dl = u >> 17;
        int off = atomicAdd(&cnt[dl], 1);
        csr[base + excl[dl] + off] = (int)(u & 0x1FFFFu);
    }
}

// ---------- agg1: Mb[v] = mean_{u in N(v)} fp8(feat[u])  -> bf16 [n][128] ----------
__global__ __launch_bounds__(256) void agg1(const unsigned char* __restrict__ Ff8,
                                            const int* __restrict__ offs,
                                            const int* __restrict__ csr,
                                            unsigned short* __restrict__ Mb, int n) {
    int t = threadIdx.x, l = t & 63, wv = t >> 6;
    int v = blockIdx.x * 4 + wv;
    if (v >= n) return;
    int beg = offs[v], end = offs[v + 1];
    float a0 = 0.f, a1 = 0.f;
    int e = beg;
    for (; e + 7 < end; e += 8) {
        unsigned short u[8];
#pragma unroll
        for (int k = 0; k < 8; ++k)
            u[k] = *(const unsigned short*)(Ff8 + (size_t)csr[e + k] * 128 + l * 2);
#pragma unroll
        for (int k = 0; k < 8; ++k) {
            float x, y;
            fp8x2_dec(u[k], x, y);
            a0 += x;
            a1 += y;
        }
    }
    for (; e < end; ++e) {
        unsigned short u0 = *(const unsigned short*)(Ff8 + (size_t)csr[e] * 128 + l * 2);
        float x, y;
        fp8x2_dec(u0, x, y);
        a0 += x;
        a1 += y;
    }
    int deg = end - beg;
    float inv = 1.0f / (float)(deg > 0 ? deg : 1);
    unsigned int o = (unsigned int)f2bf(a0 * inv) | ((unsigned int)f2bf(a1 * inv) << 16);
    *(unsigned int*)(Mb + (size_t)v * 128 + l * 2) = o;
}

// ---------- fused GEMM: h = relu([Fb|Mb]@Wb1^T) (LDS) ; Z = h@Wc^T -> Za bf16 + Zb fp8 ----------
__global__ __launch_bounds__(256) void fused_gemm(const unsigned short* __restrict__ Fb,
                                                  const unsigned short* __restrict__ Mb,
                                                  const unsigned short* __restrict__ Wb1,  // [128][256]
                                                  const unsigned short* __restrict__ Wc,   // [128][128]
                                                  unsigned short* __restrict__ Za,         // [n][64] bf16
                                                  unsigned char* __restrict__ Zb8,         // [n][64] fp8
                                                  int n) {
    __shared__ __align__(16) unsigned short hT[128][128];
    __shared__ __align__(16) unsigned short zaT[128][64];
    __shared__ __align__(16) unsigned char zbT[128][64];
    int t = threadIdx.x, l = t & 63, w = t >> 6;
    int m0 = blockIdx.x * 128;
    int lr = l & 15;
    int lk = (l >> 4) * 8;
    int rbase = (l >> 4) * 4;

    // phase 1: h = relu([Fb|Mb] @ Wb1^T), K=256
    {
        f32x4 acc[2][8];
#pragma unroll
        for (int m = 0; m < 2; ++m)
#pragma unroll
            for (int nf = 0; nf < 8; ++nf) acc[m][nf] = (f32x4){0.f, 0.f, 0.f, 0.f};
#pragma unroll
        for (int kc = 0; kc < 8; ++kc) {
            int kb = kc * 32 + lk;
            const unsigned short* src = (kb >= 128) ? Mb : Fb;
            int kcol = kb & 127;
            bf16x8 a[2];
#pragma unroll
            for (int m = 0; m < 2; ++m) {
                int row = m0 + w * 32 + m * 16 + lr;
                row = (row < n) ? row : (n - 1);
                a[m] = *(const bf16x8*)(src + (size_t)row * 128 + kcol);
            }
            bf16x8 bfr[8];
#pragma unroll
            for (int nf = 0; nf < 8; ++nf)
                bfr[nf] = *(const bf16x8*)(Wb1 + (size_t)(nf * 16 + lr) * 256 + kb);
#pragma unroll
            for (int m = 0; m < 2; ++m)
#pragma unroll
                for (int nf = 0; nf < 8; ++nf)
                    acc[m][nf] = __builtin_amdgcn_mfma_f32_16x16x32_bf16(a[m], bfr[nf], acc[m][nf], 0, 0, 0);
        }
        // stage h (relu, bf16) — wave-private rows, no barrier needed before own reads
#pragma unroll
        for (int m = 0; m < 2; ++m)
#pragma unroll
            for (int nf = 0; nf < 8; ++nf)
#pragma unroll
                for (int r = 0; r < 4; ++r)
                    hT[w * 32 + m * 16 + rbase + r][nf * 16 + lr] = f2bf(fmaxf(acc[m][nf][r], 0.f));
    }

    // phase 2: Z = h @ Wc^T, K=128 (A from LDS, wave-private rows)
    {
        f32x4 acc2[2][8];
#pragma unroll
        for (int m = 0; m < 2; ++m)
#pragma unroll
            for (int nf = 0; nf < 8; ++nf) acc2[m][nf] = (f32x4){0.f, 0.f, 0.f, 0.f};
#pragma unroll
        for (int kc = 0; kc < 4; ++kc) {
            int kb = kc * 32 + lk;
            bf16x8 a[2];
#pragma unroll
            for (int m = 0; m < 2; ++m)
                a[m] = *(const bf16x8*)&hT[w * 32 + m * 16 + lr][kb];
            bf16x8 bfr[8];
#pragma unroll
            for (int nf = 0; nf < 8; ++nf)
                bfr[nf] = *(const bf16x8*)(Wc + (size_t)(nf * 16 + lr) * 128 + kb);
#pragma unroll
            for (int m = 0; m < 2; ++m)
#pragma unroll
                for (int nf = 0; nf < 8; ++nf)
                    acc2[m][nf] = __builtin_amdgcn_mfma_f32_16x16x32_bf16(a[m], bfr[nf], acc2[m][nf], 0, 0, 0);
        }
        // stage Za (cols 0..63 bf16) and Zb (cols 64..127 fp8)
#pragma unroll
        for (int m = 0; m < 2; ++m)
#pragma unroll
            for (int nf = 0; nf < 8; ++nf)
#pragma unroll
                for (int r = 0; r < 4; ++r) {
                    float vv = acc2[m][nf][r];
                    int row = w * 32 + m * 16 + rbase + r;
                    if (nf < 4)
                        zaT[row][nf * 16 + lr] = f2bf(vv);
                    else
                        zbT[row][(nf - 4) * 16 + lr] = fp8_enc1(vv);
                }
    }
    __syncthreads();

    // coalesced global stores
#pragma unroll
    for (int c = 0; c < 4; ++c) {  // Za: 1024 chunks x 16B
        int chunk = c * 256 + t;
        int row = chunk >> 3, col8 = (chunk & 7) * 8;
        int grow = m0 + row;
        if (grow < n)
            *(bf16x8*)(Za + (size_t)grow * 64 + col8) = *(const bf16x8*)&zaT[row][col8];
    }
#pragma unroll
    for (int c = 0; c < 2; ++c) {  // Zb: 512 chunks x 16B
        int chunk = c * 256 + t;
        int row = chunk >> 2, col16 = (chunk & 3) * 16;
        int grow = m0 + row;
        if (grow < n)
            *(uint4*)(Zb8 + (size_t)grow * 64 + col16) = *(const uint4*)&zbT[row][col16];
    }
}

// ---------- agg2: out[v] = f32(Za[v]) + mean_{u} fp8(Zb[u]) ----------
__global__ __launch_bounds__(256) void agg2(const unsigned short* __restrict__ Za,
                                            const unsigned char* __restrict__ Zb8,
                                            const int* __restrict__ offs,
                                            const int* __restrict__ csr,
                                            float* __restrict__ out, int n) {
    int t = threadIdx.x, l = t & 63, wv = t >> 6;
    int hh = l >> 5, cl = l & 31;
    int v = blockIdx.x * 4 + wv;
    if (v >= n) return;
    int beg = offs[v], end = offs[v + 1];
    float a0 = 0.f, a1 = 0.f;
    int e = beg + hh;
    for (; e + 6 < end; e += 8) {  // this half-wave: e, e+2, e+4, e+6
        unsigned short u[4];
#pragma unroll
        for (int k = 0; k < 4; ++k)
            u[k] = *(const unsigned short*)(Zb8 + (size_t)csr[e + 2 * k] * 64 + cl * 2);
#pragma unroll
        for (int k = 0; k < 4; ++k) {
            float x, y;
            fp8x2_dec(u[k], x, y);
            a0 += x;
            a1 += y;
        }
    }
    for (; e < end; e += 2) {
        unsigned short u0 = *(const unsigned short*)(Zb8 + (size_t)csr[e] * 64 + cl * 2);
        float x, y;
        fp8x2_dec(u0, x, y);
        a0 += x;
        a1 += y;
    }
    a0 += __shfl_xor(a0, 32, 64);
    a1 += __shfl_xor(a1, 32, 64);
    int deg = end - beg;
    float inv = 1.0f / (float)(deg > 0 ? deg : 1);
    if (hh == 0) {
        unsigned int uz = *(const unsigned int*)(Za + (size_t)v * 64 + cl * 2);
        float2 o;
        o.x = bf2f((unsigned short)uz) + a0 * inv;
        o.y = bf2f((unsigned short)(uz >> 16)) + a1 * inv;
        *(float2*)(out + (size_t)v * 64 + cl * 2) = o;
    }
}

extern "C" void kernel_launch(void* const* d_in, const int* in_sizes, int n_in,
                              void* d_out, int out_size, void* d_ws, size_t ws_size,
                              hipStream_t stream) {
    const float* feat = (const float*)d_in[0];
    const int* esrc = (const int*)d_in[1];
    const int* edst = (const int*)d_in[2];
    const float* W0 = (const float*)d_in[3];  // [128, 256]
    const float* W1 = (const float*)d_in[4];  // [64, 256]
    float* out = (float*)d_out;

    int n = in_sizes[0] / 128;  // 100000
    int E = in_sizes[1];        // 1600000
    int NB = (n + 511) >> 9;    // 196 buckets

    char* ws = (char*)d_ws;
    size_t off = 0;
    auto alloc = [&](size_t bytes) -> void* {
        void* p = ws + off;
        off += (bytes + 255) & ~(size_t)255;
        return p;
    };
    int* offs = (int*)alloc((size_t)(n + 1) * 4);
    int* csr = (int*)alloc((size_t)E * 4);
    int* gcur = (int*)alloc((size_t)NB * 4);
    int* bbase = (int*)alloc((size_t)(NB + 1) * 4);
    unsigned short* Wb1 = (unsigned short*)alloc((size_t)128 * 256 * 2);
    unsigned short* Wb2 = (unsigned short*)alloc((size_t)128 * 128 * 2);
    unsigned short* Fb = (unsigned short*)alloc((size_t)n * 128 * 2);
    unsigned char* Ff8 = (unsigned char*)alloc((size_t)n * 128);
    unsigned short* Mb = (unsigned short*)alloc((size_t)n * 128 * 2);
    unsigned char* Zb8 = (unsigned char*)alloc((size_t)n * 64);
    unsigned int* pairs = (unsigned int*)Mb;   // pairs dead before agg1 writes Mb (9.6 MB < 25.6 MB)
    unsigned short* Za = (unsigned short*)Ff8; // Ff8 dead after agg1; Za born in fused_gemm (12.8 MB)

    int pblocks = (E + 4095) / 4096;  // 391
    int cblocks = 640;
    int nquad = n * 32;

    hipMemsetAsync(gcur, 0, (size_t)NB * 4, stream);
    megaA<<<pblocks + cblocks + 24, 256, 0, stream>>>(esrc, edst, gcur, pairs, E, NB,
                                                      feat, Fb, Ff8, nquad,
                                                      W0, Wb1, W1, Wb2, pblocks, cblocks);
    bscan<<<1, 256, 0, stream>>>(gcur, bbase, offs, n, NB, E);
    build<<<NB, 256, 0, stream>>>(pairs, gcur, bbase, offs, csr, n);

    agg1<<<(n + 3) / 4, 256, 0, stream>>>(Ff8, offs, csr, Mb, n);
    fused_gemm<<<(n + 127) / 128, 256, 0, stream>>>(Fb, Mb, Wb1, Wb2, Za, Zb8, n);
    agg2<<<(n + 3) / 4, 256, 0, stream>>>(Za, Zb8, offs, csr, out, n);
}